// Round 9
// baseline (221.392 us; speedup 1.0000x reference)
//
#include <hip/hip_runtime.h>
#include <hip/hip_bf16.h>

typedef unsigned short u16;
typedef __bf16 bf16x8 __attribute__((ext_vector_type(8)));
typedef float f32x4 __attribute__((ext_vector_type(4)));
typedef unsigned short u16x4 __attribute__((ext_vector_type(4)));

#define MFMA16(a, b, c) __builtin_amdgcn_mfma_f32_16x16x32_bf16(a, b, c, 0, 0, 0)

#define EMB 1024
#define SEQ 2048
#define NH 16
#define HD 64
#define LOG2E 1.4426950408889634f

// async global->LDS, 16B per lane; LDS dest = wave-uniform base + lane*16
#define GLOAD_LDS16(g, l) __builtin_amdgcn_global_load_lds( \
    (const __attribute__((address_space(1))) unsigned int*)(g), \
    (__attribute__((address_space(3))) unsigned int*)(l), 16, 0, 0)

__device__ __forceinline__ float b2f(u16 u) {
    union { unsigned int i; float f; } v; v.i = ((unsigned int)u) << 16; return v.f;
}
__device__ __forceinline__ u16 f2b(float f) {
    __hip_bfloat16 h = __float2bfloat16(f);
    return *reinterpret_cast<u16*>(&h);
}
__device__ __forceinline__ u16x4 pack4(float a, float b, float c, float d) {
    union { __hip_bfloat162 h2[2]; u16x4 u; } r;
    r.h2[0] = __float22bfloat162_rn(float2{a, b});
    r.h2[1] = __float22bfloat162_rn(float2{c, d});
    return r.u;
}
__device__ __forceinline__ bf16x8 ldfrag(const u16* p) {
    return *reinterpret_cast<const bf16x8*>(p);
}
__device__ __forceinline__ bf16x8 cvt8(const float* p) {
    const float4 a = *reinterpret_cast<const float4*>(p);
    const float4 b = *reinterpret_cast<const float4*>(p + 4);
    union { u16x4 q[2]; bf16x8 v; } r;
    r.q[0] = pack4(a.x, a.y, a.z, a.w);
    r.q[1] = pack4(b.x, b.y, b.z, b.w);
    return r.v;
}
// tanh via hw exp2 + rcp: rel err < 1e-6, safe for |x| < 40
__device__ __forceinline__ float fast_tanh(float x) {
    float t = __builtin_amdgcn_exp2f(x * (2.0f * LOG2E));
    return 1.0f - 2.0f * __builtin_amdgcn_rcpf(t + 1.0f);
}

// ---------------------------------------------------------------------------
// fp32 -> bf16: [x (4096x1024) | Wq | Wk | Wv | Wo] -> ws bf16, and
// J (16x64x64) -> Jb at ws + 29360128 (u16 elems)
// ---------------------------------------------------------------------------
__global__ __launch_bounds__(256) void cvt_all(
        const float* __restrict__ x,  const float* __restrict__ Wq,
        const float* __restrict__ Wk, const float* __restrict__ Wv,
        const float* __restrict__ Wo, const float* __restrict__ J,
        u16* __restrict__ dst)
{
    size_t i = ((size_t)blockIdx.x * 256 + threadIdx.x) * 8;
    const float* src; size_t off; u16* d;
    if (i < 4194304) { src = x; off = i; d = dst + i; }
    else if (i < 8388608) {
        size_t j = i - 4194304; int w = (int)(j >> 20); off = j & 1048575;
        src = (w == 0) ? Wq : (w == 1) ? Wk : (w == 2) ? Wv : Wo;
        d = dst + i;
    } else {
        off = i - 8388608; src = J; d = dst + 29360128 + off;
    }
    *(bf16x8*)d = cvt8(src + off);
}

// ---------------------------------------------------------------------------
// ROUND 9: fused QKV GEMM. One block computes Q, K, V for its 128-row m-panel
// x 128-col n-panel: A staged ONCE per K-step feeds 3x MFMA (vs 3 separate
// z-blocks each staging A) -> 3x compute per barrier-pair, A fetch 1x not 3x.
// Structure mirrors flash (the proven reg-staged single-barrier dbuf config):
// 512 thr / 8 waves / 1 block/CU, LDS dbuf 2 x (A 16KB + 3xW 48KB) = 128 KB.
// Per K-step: issue 8 int4 loads -> compute 3z x 16 MFMA x 2sub from buf[cur]
// -> ds_write into buf^1 -> ONE barrier. Waves: wm = w>>1 (32-row group),
// wn = w&1 (64-col / head). C^T accumulators, vectorized epilogues, fused-U
// (per-wave 32-row tanh(K) @ J_h^T via LDS restage) as in round 5/7.
// ---------------------------------------------------------------------------
__global__ __launch_bounds__(512) void qkv_fused(
        const u16* __restrict__ A,
        const u16* __restrict__ W0, const float* __restrict__ B0,
        const u16* __restrict__ W1, const float* __restrict__ B1,
        const u16* __restrict__ W2, const float* __restrict__ B2,
        const float* __restrict__ lam, const u16* __restrict__ Jb,
        u16* __restrict__ Qa, u16* __restrict__ Ka, u16* __restrict__ Vt)
{
    // [buf][mat][128 rows x 64 cols]; mat: 0 = A, 1+z = Wz
    __shared__ __attribute__((aligned(16))) u16 sS[2][4][128 * 64];   // 128 KB

    const int t = threadIdx.x;
    const int w = t >> 6, L = t & 63;
    const int wm = w >> 1, wn = w & 1;       // wm 0..3 (32 rows), wn 0..1 (head)
    const int lr = L & 15, lq = L >> 4;
    const int m0 = blockIdx.y * 128, n0 = blockIdx.x * 128;

    // staging: each 128x64 tile = 1024 chunks of 16B; thread t owns chunks
    // {t, 512+t}. row = c>>3, src col8 = (c&7)^(row&7) (XOR swizzle), LDS linear.
    const int c0r = t >> 3,  c0o = ((t & 7) ^ (c0r & 7)) * 8;
    const int c1  = 512 + t;
    const int c1r = c1 >> 3, c1o = ((c1 & 7) ^ (c1r & 7)) * 8;
    const u16* s0p[4], * s1p[4];
    s0p[0] = A  + (size_t)(m0 + c0r) * EMB + c0o;
    s0p[1] = W0 + (size_t)(n0 + c0r) * EMB + c0o;
    s0p[2] = W1 + (size_t)(n0 + c0r) * EMB + c0o;
    s0p[3] = W2 + (size_t)(n0 + c0r) * EMB + c0o;
    s1p[0] = A  + (size_t)(m0 + c1r) * EMB + c1o;
    s1p[1] = W0 + (size_t)(n0 + c1r) * EMB + c1o;
    s1p[2] = W1 + (size_t)(n0 + c1r) * EMB + c1o;
    s1p[3] = W2 + (size_t)(n0 + c1r) * EMB + c1o;

    f32x4 acc[3][2][4];
#pragma unroll
    for (int z = 0; z < 3; z++)
#pragma unroll
        for (int i = 0; i < 2; i++)
#pragma unroll
            for (int j = 0; j < 4; j++) { f32x4 zr = {0.f,0.f,0.f,0.f}; acc[z][i][j] = zr; }

    // prologue: stage k0 = 0 into buffer 0
    {
        int4 r0[4], r1[4];
#pragma unroll
        for (int mat = 0; mat < 4; mat++) { r0[mat] = *(const int4*)s0p[mat];
                                            r1[mat] = *(const int4*)s1p[mat]; }
#pragma unroll
        for (int mat = 0; mat < 4; mat++) {
            *(int4*)&sS[0][mat][(size_t)t * 8]  = r0[mat];
            *(int4*)&sS[0][mat][(size_t)c1 * 8] = r1[mat];
        }
    }
    __syncthreads();

    int cur = 0;
    for (int k0 = 0; k0 < EMB; k0 += 64) {
        // issue next step's loads FIRST: latency hides under 3z compute
        const bool pf = (k0 + 64) < EMB;
        int4 r0[4], r1[4];
        if (pf) {
#pragma unroll
            for (int mat = 0; mat < 4; mat++) {
                r0[mat] = *(const int4*)(s0p[mat] + k0 + 64);
                r1[mat] = *(const int4*)(s1p[mat] + k0 + 64);
            }
        }
        // compute: two 32-k sub-chunks; A-frag shared across the 3 z outputs
        __builtin_amdgcn_s_setprio(1);
#pragma unroll
        for (int s = 0; s < 2; s++) {
            bf16x8 af[2];
#pragma unroll
            for (int mi = 0; mi < 2; mi++) {
                int row = wm * 32 + mi * 16 + lr;
                af[mi] = ldfrag(&sS[cur][0][(row * 8 + ((s * 4 + lq) ^ (row & 7))) * 8]);
            }
#pragma unroll
            for (int z = 0; z < 3; z++) {
                bf16x8 bfr[4];
#pragma unroll
                for (int ni = 0; ni < 4; ni++) {
                    int row = wn * 64 + ni * 16 + lr;
                    bfr[ni] = ldfrag(
                        &sS[cur][1 + z][(row * 8 + ((s * 4 + lq) ^ (row & 7))) * 8]);
                }
                // C^T: A-op = W-frag (rows = n/d), B-op = x-frag (rows = s)
#pragma unroll
                for (int mi = 0; mi < 2; mi++)
#pragma unroll
                    for (int ni = 0; ni < 4; ni++)
                        acc[z][mi][ni] = MFMA16(bfr[ni], af[mi], acc[z][mi][ni]);
            }
        }
        __builtin_amdgcn_s_setprio(0);
        // write prefetched step into buf^1 (vmcnt wait lands here, hidden;
        // buf^1 last read before previous barrier -> safe)
        if (pf) {
#pragma unroll
            for (int mat = 0; mat < 4; mat++) {
                *(int4*)&sS[cur ^ 1][mat][(size_t)t * 8]  = r0[mat];
                *(int4*)&sS[cur ^ 1][mat][(size_t)c1 * 8] = r1[mat];
            }
        }
        __syncthreads();
        cur ^= 1;
    }

    // epilogues. sU: per-wave 32x64 tanh(K) region in dead staging LDS
    // (main loop fully fenced by its final barrier; regions wave-private)
    u16* sU = &sS[0][0][(size_t)w * 2048];

    const float lamf = lam[0];
    const float qsc = 0.125f * LOG2E, lsc = lamf * LOG2E;
    const float* biases[3] = {B0, B1, B2};
#pragma unroll
    for (int z = 0; z < 3; z++)
#pragma unroll
        for (int mi = 0; mi < 2; mi++)
#pragma unroll
            for (int ni = 0; ni < 4; ni++) {
                // C^T mapping: col (lr) = s axis, row (lq*4+r) = n/d axis
                const int sg = m0 + wm * 32 + mi * 16 + lr;
                const int ng = n0 + wn * 64 + ni * 16 + lq * 4;
                const float4 bv4 = *(const float4*)&biases[z][ng];
                const float v0 = acc[z][mi][ni][0] + bv4.x;
                const float v1 = acc[z][mi][ni][1] + bv4.y;
                const float v2 = acc[z][mi][ni][2] + bv4.z;
                const float v3 = acc[z][mi][ni][3] + bv4.w;
                const int b = sg >> 11, s0 = sg & 2047;
                const int h = ng >> 6, d0 = ng & 63;
                if (z == 0) {
                    size_t i128 = ((size_t)(b * NH + h) * SEQ + s0) * 128 + d0;
                    *(u16x4*)&Qa[i128] = pack4(v0 * qsc, v1 * qsc, v2 * qsc, v3 * qsc);
                    *(u16x4*)&Qa[i128 + 64] =
                        pack4(lsc * fast_tanh(v0), lsc * fast_tanh(v1),
                              lsc * fast_tanh(v2), lsc * fast_tanh(v3));
                } else if (z == 1) {
                    *(u16x4*)&Ka[((size_t)(b * NH + h) * SEQ + s0) * 128 + d0] =
                        pack4(v0, v1, v2, v3);
                    // stage tanh(K) into wave-private [32][64], XOR chunk swizzle
                    const int sl = mi * 16 + lr;
                    const int chunk = (d0 >> 3) ^ (sl & 7);
                    *(u16x4*)&sU[sl * 64 + chunk * 8 + (d0 & 7)] =
                        pack4(fast_tanh(v0), fast_tanh(v1),
                              fast_tanh(v2), fast_tanh(v3));
                } else {
#pragma unroll
                    for (int r = 0; r < 4; r++) {
                        float vr = (r == 0) ? v0 : (r == 1) ? v1 : (r == 2) ? v2 : v3;
                        Vt[((size_t)(b * NH + h) * HD + d0 + r) * SEQ + s0] = f2b(vr);
                    }
                }
            }

    // fused U: Ka[:,64:128] = tanh(K) @ J_h^T for this wave's 32 rows, head hn.
    // C^T: A-op = J rows (d_out), B-op = tanh rows (s). Same-wave LDS RAW only.
    {
        const int hn = (n0 >> 6) + wn;
        const u16* Jh = Jb + (size_t)hn * 4096;
        bf16x8 jf[4][2];
#pragma unroll
        for (int nt = 0; nt < 4; nt++)
#pragma unroll
            for (int s2 = 0; s2 < 2; s2++)
                jf[nt][s2] = ldfrag(&Jh[(nt * 16 + lr) * 64 + s2 * 32 + lq * 8]);
#pragma unroll
        for (int rt2 = 0; rt2 < 2; rt2++) {
            const int r32 = rt2 * 16 + lr;
            bf16x8 a0 = ldfrag(&sU[r32 * 64 + ((0 + lq) ^ (r32 & 7)) * 8]);
            bf16x8 a1 = ldfrag(&sU[r32 * 64 + ((4 + lq) ^ (r32 & 7)) * 8]);
            const int grow = m0 + wm * 32 + rt2 * 16 + lr;   // s (col axis)
            const int bb = grow >> 11, ss = grow & 2047;
            const size_t kbase = ((size_t)(bb * NH + hn) * SEQ + ss) * 128 + 64;
#pragma unroll
            for (int nt = 0; nt < 4; nt++) {
                f32x4 acc2 = {0.f, 0.f, 0.f, 0.f};
                acc2 = MFMA16(jf[nt][0], a0, acc2);
                acc2 = MFMA16(jf[nt][1], a1, acc2);
                *(u16x4*)&Ka[kbase + nt * 16 + lq * 4] =
                    pack4(acc2[0], acc2[1], acc2[2], acc2[3]);
            }
        }
    }
}

// ---------------------------------------------------------------------------
// GEMM (now only the Wo projection, mode 3): round-7 known-good structure —
// global_load_lds staging, 2 barriers per K-step, C^T accumulators,
// float4 epilogue. (48.2 µs structure; rounds 6/8 staging-schedule edits on
// this kernel both regressed -> frozen.)
// ---------------------------------------------------------------------------
template<int MI>
__global__ __launch_bounds__(256, 4) void gemm_epi(
        const u16* __restrict__ A,
        const u16* __restrict__ W0, const float* __restrict__ B0,
        float* __restrict__ out)
{
    const u16* W = W0; const float* bias = B0;

    __shared__ __attribute__((aligned(16))) u16 sA[MI * 32 * 64];
    __shared__ __attribute__((aligned(16))) u16 sB[128 * 64];

    const int t = threadIdx.x;
    const int w = t >> 6, L = t & 63;
    const int wm = w >> 1, wn = w & 1;
    const int lr = L & 15, lq = L >> 4;
    const int wbase = t & 192;                   // wave*64
    const int m0 = blockIdx.y * (MI * 32), n0 = blockIdx.x * 128;

    f32x4 acc[MI][4];
#pragma unroll
    for (int i = 0; i < MI; i++)
#pragma unroll
        for (int j = 0; j < 4; j++) { f32x4 z = {0.f, 0.f, 0.f, 0.f}; acc[i][j] = z; }

    for (int k0 = 0; k0 < EMB; k0 += 64) {
        __syncthreads();
#pragma unroll
        for (int q = 0; q < MI; q++) {
            int c = q * 256 + t;
            int row = c >> 3, cc = c & 7;
            int col8 = cc ^ (row & 7);
            GLOAD_LDS16(&A[(size_t)(m0 + row) * EMB + k0 + col8 * 8],
                        &sA[(q * 256 + wbase) * 8]);
        }
#pragma unroll
        for (int q = 0; q < 4; q++) {
            int c = q * 256 + t;
            int row = c >> 3, cc = c & 7;
            int col8 = cc ^ (row & 7);
            GLOAD_LDS16(&W[(size_t)(n0 + row) * EMB + k0 + col8 * 8],
                        &sB[(q * 256 + wbase) * 8]);
        }
        __syncthreads();
#pragma unroll
        for (int s = 0; s < 2; s++) {
            bf16x8 af[MI], bfr[4];
#pragma unroll
            for (int mi = 0; mi < MI; mi++) {
                int row = wm * (MI * 16) + mi * 16 + lr;
                af[mi] = ldfrag(&sA[(row * 8 + ((s * 4 + lq) ^ (row & 7))) * 8]);
            }
#pragma unroll
            for (int ni = 0; ni < 4; ni++) {
                int row = wn * 64 + ni * 16 + lr;
                bfr[ni] = ldfrag(&sB[(row * 8 + ((s * 4 + lq) ^ (row & 7))) * 8]);
            }
#pragma unroll
            for (int mi = 0; mi < MI; mi++)
#pragma unroll
                for (int ni = 0; ni < 4; ni++)
                    acc[mi][ni] = MFMA16(bfr[ni], af[mi], acc[mi][ni]);
        }
    }

#pragma unroll
    for (int mi = 0; mi < MI; mi++)
#pragma unroll
        for (int ni = 0; ni < 4; ni++) {
            const int sg = m0 + wm * (MI * 16) + mi * 16 + lr;
            const int ng = n0 + wn * 64 + ni * 16 + lq * 4;
            const float4 bv4 = *(const float4*)&bias[ng];
            float4 o = {acc[mi][ni][0] + bv4.x, acc[mi][ni][1] + bv4.y,
                        acc[mi][ni][2] + bv4.z, acc[mi][ni][3] + bv4.w};
            *(float4*)&out[(size_t)sg * EMB + ng] = o;
        }
}

// ---------------------------------------------------------------------------
// Causal flash, S^T formulation, BM=128, 256 blocks x 512 thr (8 waves),
// segments (qt=p, qt=15-p) per block = uniform 17 k-tiles of KVBLK=128.
// (unchanged from round 4)
// ---------------------------------------------------------------------------
__global__ __launch_bounds__(512) void flash(
        const u16* __restrict__ Qa, const u16* __restrict__ Ka,
        const u16* __restrict__ Vt, u16* __restrict__ attn)
{
    __shared__ __attribute__((aligned(16))) u16 sK[2][128 * 128];  // 64 KB
    __shared__ __attribute__((aligned(16))) u16 sVt[2][64 * 128];  // 32 KB
    __shared__ __attribute__((aligned(16))) u16 sP[128 * 136];     // 34 KB
    __shared__ float sLs[2][4][64][2];                             // 4 KB

    const int t = threadIdx.x, w = t >> 6, L = t & 63, lr = L & 15, lq = L >> 4;
    const int wq = w & 3, wk = w >> 2;
    const int bh = blockIdx.x & 31, p = blockIdx.x >> 5;
    const int i_l = wq * 16 + lr;           // lane's q-row within a 64-set
    const u16* Kbase = Ka + (size_t)bh * SEQ * 128;
    const u16* Vbase = Vt + (size_t)bh * HD * SEQ;
    const int b = bh >> 4, h = bh & 15;
    float* sOt = reinterpret_cast<float*>(sK);   // 32 KB combine buffer (fits)

    const u16* kq[4];
#pragma unroll
    for (int q = 0; q < 4; q++) {
        int c = q * 512 + t;
        int row = c >> 4, cc = c & 15;
        kq[q] = Kbase + (size_t)row * 128 + (cc ^ (row & 15)) * 8;
    }
    const u16* vq[2];
#pragma unroll
    for (int q = 0; q < 2; q++) {
        int c = q * 512 + t;
        int d = c >> 4, cc = c & 15;
        vq[q] = Vbase + (size_t)d * SEQ + (cc ^ (d & 7)) * 8;
    }

#pragma unroll 1
    for (int seg = 0; seg < 2; seg++) {
        const int qt = seg ? 15 - p : p;
        const int qm = qt * 128;

        bf16x8 qf[2][4];
#pragma unroll
        for (int g = 0; g < 2; g++) {
            const u16* qrow = Qa + ((size_t)bh * SEQ + qm + g * 64 + i_l) * 128;
#pragma unroll
            for (int s = 0; s < 4; s++) qf[g][s] = ldfrag(qrow + s * 32 + lq * 8);
        }

        f32x4 Ot[2][4];
#pragma unroll
        for (int g = 0; g < 2; g++)
#pragma unroll
            for (int i = 0; i < 4; i++) { f32x4 z = {0.f, 0.f, 0.f, 0.f}; Ot[g][i] = z; }
        float lsum[2] = {0.f, 0.f};

        {
            int4 a0 = *(const int4*)kq[0];
            int4 a1 = *(const int4*)kq[1];
            int4 a2 = *(const int4*)kq[2];
            int4 a3 = *(const int4*)kq[3];
            int4 b0 = *(const int4*)vq[0];
            int4 b1 = *(const int4*)vq[1];
            *(int4*)&sK[0][(size_t)(0 * 512 + t) * 8] = a0;
            *(int4*)&sK[0][(size_t)(1 * 512 + t) * 8] = a1;
            *(int4*)&sK[0][(size_t)(2 * 512 + t) * 8] = a2;
            *(int4*)&sK[0][(size_t)(3 * 512 + t) * 8] = a3;
            *(int4*)&sVt[0][(size_t)(0 * 512 + t) * 8] = b0;
            *(int4*)&sVt[0][(size_t)(1 * 512 + t) * 8] = b1;
        }
        __syncthreads();

        int cur = 0;
        for (int kt = 0; kt <= qt; kt++) {
            const bool pf = kt < qt;
            int4 rk0, rk1, rk2, rk3, rv0, rv1;
            if (pf) {
                const int kn = (kt + 1) * 128;
                rk0 = *(const int4*)(kq[0] + (size_t)kn * 128);
                rk1 = *(const int4*)(kq[1] + (size_t)kn * 128);
                rk2 = *(const int4*)(kq[2] + (size_t)kn * 128);
                rk3 = *(const int4*)(kq[3] + (size_t)kn * 128);
                rv0 = *(const int4*)(vq[0] + kn);
                rv1 = *(const int4*)(vq[1] + kn);
            }
            const u16* sKc = sK[cur];
            const u16* sVc = sVt[cur];

            f32x4 sc[2][4];
#pragma unroll
            for (int g = 0; g < 2; g++)
#pragma unroll
                for (int m = 0; m < 4; m++) { f32x4 z = {0.f,0.f,0.f,0.f}; sc[g][m] = z; }
            __builtin_amdgcn_s_setprio(1);
#pragma unroll
            for (int mt2 = 0; mt2 < 4; mt2++) {
                int j = wk * 64 + mt2 * 16 + lr;
#pragma unroll
                for (int s = 0; s < 4; s++) {
                    bf16x8 kf = ldfrag(&sKc[(j * 16 + ((s * 4 + lq) ^ (j & 15))) * 8]);
                    sc[0][mt2] = MFMA16(kf, qf[0][s], sc[0][mt2]);
                    sc[1][mt2] = MFMA16(kf, qf[1][s], sc[1][mt2]);
                }
            }
            __builtin_amdgcn_s_setprio(0);
            if (kt == qt) {
#pragma unroll
                for (int mt2 = 0; mt2 < 4; mt2++)
#pragma unroll
                    for (int r = 0; r < 4; r++) {
                        int jj = wk * 64 + mt2 * 16 + lq * 4 + r;
                        if (jj > i_l)      sc[0][mt2][r] = -INFINITY;
                        if (jj > 64 + i_l) sc[1][mt2][r] = -INFINITY;
                    }
            }
#pragma unroll
            for (int g = 0; g < 2; g++) {
#pragma unroll
                for (int mt2 = 0; mt2 < 4; mt2++) {
                    float e0 = __builtin_amdgcn_exp2f(sc[g][mt2][0]);
                    float e1 = __builtin_amdgcn_exp2f(sc[g][mt2][1]);
                    float e2 = __builtin_amdgcn_exp2f(sc[g][mt2][2]);
                    float e3 = __builtin_amdgcn_exp2f(sc[g][mt2][3]);
                    lsum[g] += (e0 + e1) + (e2 + e3);
                    *(u16x4*)&sP[(g * 64 + i_l) * 136 + wk * 64 + mt2 * 16 + lq * 4] =
                        pack4(e0, e1, e2, e3);
                }
            }
            __builtin_amdgcn_s_setprio(1);
#pragma unroll
            for (int s2l = 0; s2l < 2; s2l++) {
                bf16x8 pf0 = ldfrag(&sP[(i_l) * 136 + wk * 64 + s2l * 32 + lq * 8]);
                bf16x8 pf1 = ldfrag(&sP[(64 + i_l) * 136 + wk * 64 + s2l * 32 + lq * 8]);
#pragma unroll
                for (int mt = 0; mt < 4; mt++) {
                    int d = mt * 16 + lr;
                    bf16x8 vf = ldfrag(
                        &sVc[(d * 16 + ((wk * 8 + s2l * 4 + lq) ^ (d & 7))) * 8]);
                    Ot[0][mt] = MFMA16(vf, pf0, Ot[0][mt]);
                    Ot[1][mt] = MFMA16(vf, pf1, Ot[1][mt]);
                }
            }
            __builtin_amdgcn_s_setprio(0);
            if (pf) {
                *(int4*)&sK[cur ^ 1][(size_t)(0 * 512 + t) * 8] = rk0;
                *(int4*)&sK[cur ^ 1][(size_t)(1 * 512 + t) * 8] = rk1;
                *(int4*)&sK[cur ^ 1][(size_t)(2 * 512 + t) * 8] = rk2;
                *(int4*)&sK[cur ^ 1][(size_t)(3 * 512 + t) * 8] = rk3;
                *(int4*)&sVt[cur ^ 1][(size_t)(0 * 512 + t) * 8] = rv0;
                *(int4*)&sVt[cur ^ 1][(size_t)(1 * 512 + t) * 8] = rv1;
            }
            __syncthreads();
            cur ^= 1;
        }

        // ---- combine k-split partials and write this segment's output ----
#pragma unroll
        for (int g = 0; g < 2; g++) {
            lsum[g] += __shfl_xor(lsum[g], 16);
            lsum[g] += __shfl_xor(lsum[g], 32);
            sLs[wk][wq][L][g] = lsum[g];
        }
        if (wk == 1) {
            float* dst = &sOt[wq * 64 + L];
#pragma unroll
            for (int g = 0; g < 2; g++)
#pragma unroll
                for (int mt = 0; mt < 4; mt++)
#pragma unroll
                    for (int r = 0; r < 4; r++)
                        dst[256 * (g * 16 + mt * 4 + r)] = Ot[g][mt][r];
        }
        __syncthreads();
        if (wk == 0) {
            const float* src = &sOt[wq * 64 + L];
#pragma unroll
            for (int g = 0; g < 2; g++) {
                float ls = lsum[g] + sLs[1][wq][L][g];
                const float r0 = __builtin_amdgcn_rcpf(ls);
                const float inv = r0 * (2.0f - ls * r0);  // NR refine
                const size_t base =
                    ((size_t)(b * SEQ + qm + g * 64 + i_l)) * EMB + h * HD;
#pragma unroll
                for (int mt = 0; mt < 4; mt++)
                    *(u16x4*)&attn[base + mt * 16 + lq * 4] = pack4(
                        (Ot[g][mt][0] + src[256 * (g * 16 + mt * 4 + 0)]) * inv,
                        (Ot[g][mt][1] + src[256 * (g * 16 + mt * 4 + 1)]) * inv,
                        (Ot[g][mt][2] + src[256 * (g * 16 + mt * 4 + 2)]) * inv,
                        (Ot[g][mt][3] + src[256 * (g * 16 + mt * 4 + 3)]) * inv);
            }
        }
        __syncthreads();   // protect sOt/sLs before next segment's staging
    }
}

// ---------------------------------------------------------------------------
extern "C" void kernel_launch(void* const* d_in, const int* in_sizes, int n_in,
                              void* d_out, int out_size, void* d_ws, size_t ws_size,
                              hipStream_t stream)
{
    const float* x   = (const float*)d_in[0];
    const float* Wq  = (const float*)d_in[1];
    const float* bq  = (const float*)d_in[2];
    const float* Wk  = (const float*)d_in[3];
    const float* bk  = (const float*)d_in[4];
    const float* Wv  = (const float*)d_in[5];
    const float* bv  = (const float*)d_in[6];
    const float* Wo  = (const float*)d_in[7];
    const float* bo  = (const float*)d_in[8];
    const float* J   = (const float*)d_in[9];
    const float* lam = (const float*)d_in[10];

    u16* ws  = (u16*)d_ws;
    u16* xb  = ws;                                   // 4096*1024 bf16 (reused as attn)
    u16* Wqb = xb  + (size_t)4096 * 1024;
    u16* Wkb = Wqb + (size_t)1024 * 1024;
    u16* Wvb = Wkb + (size_t)1024 * 1024;
    u16* Wob = Wvb + (size_t)1024 * 1024;
    u16* Qa  = Wob + (size_t)1024 * 1024;            // 32*2048*128
    u16* Ka  = Qa  + (size_t)32 * 2048 * 128;        // 32*2048*128
    u16* Vt  = Ka  + (size_t)32 * 2048 * 128;        // 32*64*2048 (b,h,d,s)
    u16* Jb  = Vt  + (size_t)32 * 64 * 2048;         // 16*64*64 bf16 (= ws+29360128)
    u16* attn = xb;                                  // alias: xb dead after QKV
    float* dout = (float*)d_out;

    dim3 blk(256);
    // fp32 -> bf16 for x, the four weight matrices, and J
    cvt_all<<<dim3(4128), blk, 0, stream>>>(x, Wq, Wk, Wv, Wo, J, ws);
    // fused Q/K/V projections + Ka[:,64:128]: 256 blocks x 512 thr
    qkv_fused<<<dim3(8, 32), dim3(512), 0, stream>>>(
        xb, Wqb, bq, Wkb, bk, Wvb, bv, lam, Jb, Qa, Ka, Vt);
    // causal flash attention: 256 blocks x 512 thr, qt pair (p, 15-p) per block
    flash<<<dim3(256), dim3(512), 0, stream>>>(Qa, Ka, Vt, attn);
    // output projection (64-row tiles -> 512 blocks for occupancy)
    gemm_epi<2><<<dim3(8, 64), blk, 0, stream>>>(attn, Wob, bo, dout);
}

// Round 10
// 195.773 us; speedup vs baseline: 1.1309x; 1.1309x over previous
//
#include <hip/hip_runtime.h>
#include <hip/hip_bf16.h>

typedef unsigned short u16;
typedef __bf16 bf16x8 __attribute__((ext_vector_type(8)));
typedef float f32x4 __attribute__((ext_vector_type(4)));
typedef unsigned short u16x4 __attribute__((ext_vector_type(4)));

#define MFMA16(a, b, c) __builtin_amdgcn_mfma_f32_16x16x32_bf16(a, b, c, 0, 0, 0)

#define EMB 1024
#define SEQ 2048
#define NH 16
#define HD 64
#define LOG2E 1.4426950408889634f

// async global->LDS, 16B per lane; LDS dest = wave-uniform base + lane*16
#define GLOAD_LDS16(g, l) __builtin_amdgcn_global_load_lds( \
    (const __attribute__((address_space(1))) unsigned int*)(g), \
    (__attribute__((address_space(3))) unsigned int*)(l), 16, 0, 0)

__device__ __forceinline__ float b2f(u16 u) {
    union { unsigned int i; float f; } v; v.i = ((unsigned int)u) << 16; return v.f;
}
__device__ __forceinline__ u16 f2b(float f) {
    __hip_bfloat16 h = __float2bfloat16(f);
    return *reinterpret_cast<u16*>(&h);
}
__device__ __forceinline__ u16x4 pack4(float a, float b, float c, float d) {
    union { __hip_bfloat162 h2[2]; u16x4 u; } r;
    r.h2[0] = __float22bfloat162_rn(float2{a, b});
    r.h2[1] = __float22bfloat162_rn(float2{c, d});
    return r.u;
}
__device__ __forceinline__ bf16x8 ldfrag(const u16* p) {
    return *reinterpret_cast<const bf16x8*>(p);
}
__device__ __forceinline__ bf16x8 cvt8(const float* p) {
    const float4 a = *reinterpret_cast<const float4*>(p);
    const float4 b = *reinterpret_cast<const float4*>(p + 4);
    union { u16x4 q[2]; bf16x8 v; } r;
    r.q[0] = pack4(a.x, a.y, a.z, a.w);
    r.q[1] = pack4(b.x, b.y, b.z, b.w);
    return r.v;
}
// tanh via hw exp2 + rcp: rel err < 1e-6, safe for |x| < 40
__device__ __forceinline__ float fast_tanh(float x) {
    float t = __builtin_amdgcn_exp2f(x * (2.0f * LOG2E));
    return 1.0f - 2.0f * __builtin_amdgcn_rcpf(t + 1.0f);
}

// ---------------------------------------------------------------------------
// fp32 -> bf16: [x (4096x1024) | Wq | Wk | Wv | Wo] -> ws bf16, and
// J (16x64x64) -> Jb at ws + 29360128 (u16 elems)
// ---------------------------------------------------------------------------
__global__ __launch_bounds__(256) void cvt_all(
        const float* __restrict__ x,  const float* __restrict__ Wq,
        const float* __restrict__ Wk, const float* __restrict__ Wv,
        const float* __restrict__ Wo, const float* __restrict__ J,
        u16* __restrict__ dst)
{
    size_t i = ((size_t)blockIdx.x * 256 + threadIdx.x) * 8;
    const float* src; size_t off; u16* d;
    if (i < 4194304) { src = x; off = i; d = dst + i; }
    else if (i < 8388608) {
        size_t j = i - 4194304; int w = (int)(j >> 20); off = j & 1048575;
        src = (w == 0) ? Wq : (w == 1) ? Wk : (w == 2) ? Wv : Wo;
        d = dst + i;
    } else {
        off = i - 8388608; src = J; d = dst + 29360128 + off;
    }
    *(bf16x8*)d = cvt8(src + off);
}

// ---------------------------------------------------------------------------
// ROUND 10: QKV GEMM, pipelined reg-staging with sched_barrier fences.
// Fixes all three diagnosed failure causes of R6/R8/R9:
//  (i)  load-sinking: sched_barrier(0) after the load-issue group pins the
//       prefetch loads BEFORE compute; their vmcnt wait lands at the ds_write
//       after compute (first use) -> latency hidden under 16 MFMAs.
//  (ii) no global_load_lds in this kernel -> no conservative vmcnt(0) drain
//       before ds_reads possible.
//  (iii) MI=2 tile: LDS dbuf = 2x(8KB A + 16KB B) = 48KB -> 3 blocks/CU kept
//       (R6/R8 lost a block and with it inter-block latency hiding).
// Tile 64 x 128, BK=64, 4 waves (2m x 2n), one barrier per K-step, branchless
// clamped prefetch (last step re-loads, writes dead buffer - harmless).
// C^T accumulators + vectorized epilogues + per-wave fused-U (rounds 5/7).
// grid (8, 64, 3): z selects Q/K/V.
// ---------------------------------------------------------------------------
__global__ __launch_bounds__(256, 3) void qkv_gemm(
        const u16* __restrict__ A,
        const u16* __restrict__ W0, const float* __restrict__ B0,
        const u16* __restrict__ W1, const float* __restrict__ B1,
        const u16* __restrict__ W2, const float* __restrict__ B2,
        const float* __restrict__ lam, const u16* __restrict__ Jb,
        u16* __restrict__ Qa, u16* __restrict__ Ka, u16* __restrict__ Vt)
{
    const int mode = blockIdx.z;
    const u16* W; const float* bias;
    if (mode == 0)      { W = W0; bias = B0; }
    else if (mode == 1) { W = W1; bias = B1; }
    else                { W = W2; bias = B2; }

    __shared__ __attribute__((aligned(16))) u16 sA[2][64 * 64];    // 16 KB
    __shared__ __attribute__((aligned(16))) u16 sB[2][128 * 64];   // 32 KB

    const int t = threadIdx.x;
    const int w = t >> 6, L = t & 63;
    const int wm = w >> 1, wn = w & 1;
    const int lr = L & 15, lq = L >> 4;
    const int m0 = blockIdx.y * 64, n0 = blockIdx.x * 128;

    // per-thread staging addresses (pre-swizzled source, linear LDS dest):
    // A tile 64x64 = 512 chunks of 16B, thread owns {t, 256+t};
    // B tile 128x64 = 1024 chunks, thread owns {t, 256+t, 512+t, 768+t}.
    // chunk c: row = c>>3, col8 = (c&7) ^ (row&7)
    const u16* aptr[2];
#pragma unroll
    for (int q = 0; q < 2; q++) {
        int c = q * 256 + t;
        int row = c >> 3, col8 = (c & 7) ^ (row & 7);
        aptr[q] = &A[(size_t)(m0 + row) * EMB + col8 * 8];
    }
    const u16* bptr[4];
#pragma unroll
    for (int q = 0; q < 4; q++) {
        int c = q * 256 + t;
        int row = c >> 3, col8 = (c & 7) ^ (row & 7);
        bptr[q] = &W[(size_t)(n0 + row) * EMB + col8 * 8];
    }

    f32x4 acc[2][4];
#pragma unroll
    for (int i = 0; i < 2; i++)
#pragma unroll
        for (int j = 0; j < 4; j++) { f32x4 z = {0.f, 0.f, 0.f, 0.f}; acc[i][j] = z; }

    // prologue: load k0=0 -> write buf0 -> barrier (latency exposed once)
    {
        int4 ra0 = *(const int4*)aptr[0];
        int4 ra1 = *(const int4*)aptr[1];
        int4 rb0 = *(const int4*)bptr[0];
        int4 rb1 = *(const int4*)bptr[1];
        int4 rb2 = *(const int4*)bptr[2];
        int4 rb3 = *(const int4*)bptr[3];
        *(int4*)&sA[0][(size_t)(0 * 256 + t) * 8] = ra0;
        *(int4*)&sA[0][(size_t)(1 * 256 + t) * 8] = ra1;
        *(int4*)&sB[0][(size_t)(0 * 256 + t) * 8] = rb0;
        *(int4*)&sB[0][(size_t)(1 * 256 + t) * 8] = rb1;
        *(int4*)&sB[0][(size_t)(2 * 256 + t) * 8] = rb2;
        *(int4*)&sB[0][(size_t)(3 * 256 + t) * 8] = rb3;
    }
    __syncthreads();

    int cur = 0;
    for (int k0 = 0; k0 < EMB; k0 += 64) {
        // branchless clamped prefetch: last step re-loads current (dead write)
        const int kn = (k0 + 64 < EMB) ? (k0 + 64) : k0;
        int4 ra0 = *(const int4*)(aptr[0] + kn);
        int4 ra1 = *(const int4*)(aptr[1] + kn);
        int4 rb0 = *(const int4*)(bptr[0] + kn);
        int4 rb1 = *(const int4*)(bptr[1] + kn);
        int4 rb2 = *(const int4*)(bptr[2] + kn);
        int4 rb3 = *(const int4*)(bptr[3] + kn);
        // pin: loads ISSUE here, before compute (anti-sink fence, rule 18/T19)
        __builtin_amdgcn_sched_barrier(0);

        const u16* sAc = sA[cur];
        const u16* sBc = sB[cur];
#pragma unroll
        for (int s = 0; s < 2; s++) {
            bf16x8 af[2], bfr[4];
#pragma unroll
            for (int mi = 0; mi < 2; mi++) {
                int row = wm * 32 + mi * 16 + lr;
                af[mi] = ldfrag(&sAc[(row * 8 + ((s * 4 + lq) ^ (row & 7))) * 8]);
            }
#pragma unroll
            for (int ni = 0; ni < 4; ni++) {
                int row = wn * 64 + ni * 16 + lr;
                bfr[ni] = ldfrag(&sBc[(row * 8 + ((s * 4 + lq) ^ (row & 7))) * 8]);
            }
            // C^T: A-op = W-frag (rows = n/d), B-op = x-frag (rows = s)
#pragma unroll
            for (int mi = 0; mi < 2; mi++)
#pragma unroll
                for (int ni = 0; ni < 4; ni++)
                    acc[mi][ni] = MFMA16(bfr[ni], af[mi], acc[mi][ni]);
        }
        // pin: ds_writes stay AFTER compute; vmcnt wait for the prefetch
        // loads lands here, fully hidden under the 16 MFMAs above
        __builtin_amdgcn_sched_barrier(0);
        *(int4*)&sA[cur ^ 1][(size_t)(0 * 256 + t) * 8] = ra0;
        *(int4*)&sA[cur ^ 1][(size_t)(1 * 256 + t) * 8] = ra1;
        *(int4*)&sB[cur ^ 1][(size_t)(0 * 256 + t) * 8] = rb0;
        *(int4*)&sB[cur ^ 1][(size_t)(1 * 256 + t) * 8] = rb1;
        *(int4*)&sB[cur ^ 1][(size_t)(2 * 256 + t) * 8] = rb2;
        *(int4*)&sB[cur ^ 1][(size_t)(3 * 256 + t) * 8] = rb3;
        __syncthreads();   // one barrier per K-step
        cur ^= 1;
    }

    // epilogues. sU: wave-private 32x64 tanh(K) region in dead sB[0] (16 KB);
    // all main-loop LDS traffic fenced by the loop's final barrier.
    u16* sU = &sB[0][(size_t)w * 2048];

    const float lamf = lam[0];
    const float qsc = 0.125f * LOG2E, lsc = lamf * LOG2E;
#pragma unroll
    for (int mi = 0; mi < 2; mi++)
#pragma unroll
        for (int ni = 0; ni < 4; ni++) {
            // C^T mapping: col (lr) = s axis, row (lq*4+r) = n/d axis
            const int sg = m0 + wm * 32 + mi * 16 + lr;
            const int ng = n0 + wn * 64 + ni * 16 + lq * 4;   // 4 consecutive n
            const float4 bv4 = *(const float4*)&bias[ng];
            const float v0 = acc[mi][ni][0] + bv4.x;
            const float v1 = acc[mi][ni][1] + bv4.y;
            const float v2 = acc[mi][ni][2] + bv4.z;
            const float v3 = acc[mi][ni][3] + bv4.w;
            const int b = sg >> 11, s0 = sg & 2047;
            const int h = ng >> 6, d0 = ng & 63;
            if (mode == 0) {
                size_t i128 = ((size_t)(b * NH + h) * SEQ + s0) * 128 + d0;
                *(u16x4*)&Qa[i128] = pack4(v0 * qsc, v1 * qsc, v2 * qsc, v3 * qsc);
                *(u16x4*)&Qa[i128 + 64] =
                    pack4(lsc * fast_tanh(v0), lsc * fast_tanh(v1),
                          lsc * fast_tanh(v2), lsc * fast_tanh(v3));
            } else if (mode == 1) {
                *(u16x4*)&Ka[((size_t)(b * NH + h) * SEQ + s0) * 128 + d0] =
                    pack4(v0, v1, v2, v3);
                // stage tanh(K) into wave-private [32][64], XOR chunk swizzle
                const int sl = mi * 16 + lr;
                const int chunk = (d0 >> 3) ^ (sl & 7);
                *(u16x4*)&sU[sl * 64 + chunk * 8 + (d0 & 7)] =
                    pack4(fast_tanh(v0), fast_tanh(v1),
                          fast_tanh(v2), fast_tanh(v3));
            } else {
#pragma unroll
                for (int r = 0; r < 4; r++) {
                    float vr = (r == 0) ? v0 : (r == 1) ? v1 : (r == 2) ? v2 : v3;
                    Vt[((size_t)(b * NH + h) * HD + d0 + r) * SEQ + s0] = f2b(vr);
                }
            }
        }

    // fused U: Ka[:,64:128] = tanh(K) @ J_h^T for this wave's 32 rows,
    // head hn = n0/64 + wn. C^T: A-op = J rows (d_out), B-op = tanh rows (s).
    // Same-wave LDS RAW only (sU wave-private).
    if (mode == 1) {
        const int hn = (n0 >> 6) + wn;
        const u16* Jh = Jb + (size_t)hn * 4096;
        bf16x8 jf[4][2];
#pragma unroll
        for (int nt = 0; nt < 4; nt++)
#pragma unroll
            for (int s2 = 0; s2 < 2; s2++)
                jf[nt][s2] = ldfrag(&Jh[(nt * 16 + lr) * 64 + s2 * 32 + lq * 8]);
#pragma unroll
        for (int rt2 = 0; rt2 < 2; rt2++) {
            const int r32 = rt2 * 16 + lr;
            bf16x8 a0 = ldfrag(&sU[r32 * 64 + ((0 + lq) ^ (r32 & 7)) * 8]);
            bf16x8 a1 = ldfrag(&sU[r32 * 64 + ((4 + lq) ^ (r32 & 7)) * 8]);
            const int grow = m0 + wm * 32 + rt2 * 16 + lr;   // s (col axis)
            const int bb = grow >> 11, ss = grow & 2047;
            const size_t kbase = ((size_t)(bb * NH + hn) * SEQ + ss) * 128 + 64;
#pragma unroll
            for (int nt = 0; nt < 4; nt++) {
                f32x4 acc2 = {0.f, 0.f, 0.f, 0.f};
                acc2 = MFMA16(jf[nt][0], a0, acc2);
                acc2 = MFMA16(jf[nt][1], a1, acc2);
                *(u16x4*)&Ka[kbase + nt * 16 + lq * 4] =
                    pack4(acc2[0], acc2[1], acc2[2], acc2[3]);
            }
        }
    }
}

// ---------------------------------------------------------------------------
// GEMM (Wo projection, mode 3): round-7 known-good structure, FROZEN —
// global_load_lds staging, 2 barriers per K-step, C^T accumulators,
// float4 epilogue. (Rounds 6/8 staging-schedule edits here regressed.)
// ---------------------------------------------------------------------------
template<int MI>
__global__ __launch_bounds__(256, 4) void gemm_epi(
        const u16* __restrict__ A,
        const u16* __restrict__ W0, const float* __restrict__ B0,
        float* __restrict__ out)
{
    const u16* W = W0; const float* bias = B0;

    __shared__ __attribute__((aligned(16))) u16 sA[MI * 32 * 64];
    __shared__ __attribute__((aligned(16))) u16 sB[128 * 64];

    const int t = threadIdx.x;
    const int w = t >> 6, L = t & 63;
    const int wm = w >> 1, wn = w & 1;
    const int lr = L & 15, lq = L >> 4;
    const int wbase = t & 192;                   // wave*64
    const int m0 = blockIdx.y * (MI * 32), n0 = blockIdx.x * 128;

    f32x4 acc[MI][4];
#pragma unroll
    for (int i = 0; i < MI; i++)
#pragma unroll
        for (int j = 0; j < 4; j++) { f32x4 z = {0.f, 0.f, 0.f, 0.f}; acc[i][j] = z; }

    for (int k0 = 0; k0 < EMB; k0 += 64) {
        __syncthreads();
#pragma unroll
        for (int q = 0; q < MI; q++) {
            int c = q * 256 + t;
            int row = c >> 3, cc = c & 7;
            int col8 = cc ^ (row & 7);
            GLOAD_LDS16(&A[(size_t)(m0 + row) * EMB + k0 + col8 * 8],
                        &sA[(q * 256 + wbase) * 8]);
        }
#pragma unroll
        for (int q = 0; q < 4; q++) {
            int c = q * 256 + t;
            int row = c >> 3, cc = c & 7;
            int col8 = cc ^ (row & 7);
            GLOAD_LDS16(&W[(size_t)(n0 + row) * EMB + k0 + col8 * 8],
                        &sB[(q * 256 + wbase) * 8]);
        }
        __syncthreads();
#pragma unroll
        for (int s = 0; s < 2; s++) {
            bf16x8 af[MI], bfr[4];
#pragma unroll
            for (int mi = 0; mi < MI; mi++) {
                int row = wm * (MI * 16) + mi * 16 + lr;
                af[mi] = ldfrag(&sA[(row * 8 + ((s * 4 + lq) ^ (row & 7))) * 8]);
            }
#pragma unroll
            for (int ni = 0; ni < 4; ni++) {
                int row = wn * 64 + ni * 16 + lr;
                bfr[ni] = ldfrag(&sB[(row * 8 + ((s * 4 + lq) ^ (row & 7))) * 8]);
            }
#pragma unroll
            for (int mi = 0; mi < MI; mi++)
#pragma unroll
                for (int ni = 0; ni < 4; ni++)
                    acc[mi][ni] = MFMA16(bfr[ni], af[mi], acc[mi][ni]);
        }
    }

#pragma unroll
    for (int mi = 0; mi < MI; mi++)
#pragma unroll
        for (int ni = 0; ni < 4; ni++) {
            const int sg = m0 + wm * (MI * 16) + mi * 16 + lr;
            const int ng = n0 + wn * 64 + ni * 16 + lq * 4;
            const float4 bv4 = *(const float4*)&bias[ng];
            float4 o = {acc[mi][ni][0] + bv4.x, acc[mi][ni][1] + bv4.y,
                        acc[mi][ni][2] + bv4.z, acc[mi][ni][3] + bv4.w};
            *(float4*)&out[(size_t)sg * EMB + ng] = o;
        }
}

// ---------------------------------------------------------------------------
// Causal flash, S^T formulation, BM=128, 256 blocks x 512 thr (8 waves),
// segments (qt=p, qt=15-p) per block = uniform 17 k-tiles of KVBLK=128.
// (unchanged from round 4)
// ---------------------------------------------------------------------------
__global__ __launch_bounds__(512) void flash(
        const u16* __restrict__ Qa, const u16* __restrict__ Ka,
        const u16* __restrict__ Vt, u16* __restrict__ attn)
{
    __shared__ __attribute__((aligned(16))) u16 sK[2][128 * 128];  // 64 KB
    __shared__ __attribute__((aligned(16))) u16 sVt[2][64 * 128];  // 32 KB
    __shared__ __attribute__((aligned(16))) u16 sP[128 * 136];     // 34 KB
    __shared__ float sLs[2][4][64][2];                             // 4 KB

    const int t = threadIdx.x, w = t >> 6, L = t & 63, lr = L & 15, lq = L >> 4;
    const int wq = w & 3, wk = w >> 2;
    const int bh = blockIdx.x & 31, p = blockIdx.x >> 5;
    const int i_l = wq * 16 + lr;           // lane's q-row within a 64-set
    const u16* Kbase = Ka + (size_t)bh * SEQ * 128;
    const u16* Vbase = Vt + (size_t)bh * HD * SEQ;
    const int b = bh >> 4, h = bh & 15;
    float* sOt = reinterpret_cast<float*>(sK);   // 32 KB combine buffer (fits)

    const u16* kq[4];
#pragma unroll
    for (int q = 0; q < 4; q++) {
        int c = q * 512 + t;
        int row = c >> 4, cc = c & 15;
        kq[q] = Kbase + (size_t)row * 128 + (cc ^ (row & 15)) * 8;
    }
    const u16* vq[2];
#pragma unroll
    for (int q = 0; q < 2; q++) {
        int c = q * 512 + t;
        int d = c >> 4, cc = c & 15;
        vq[q] = Vbase + (size_t)d * SEQ + (cc ^ (d & 7)) * 8;
    }

#pragma unroll 1
    for (int seg = 0; seg < 2; seg++) {
        const int qt = seg ? 15 - p : p;
        const int qm = qt * 128;

        bf16x8 qf[2][4];
#pragma unroll
        for (int g = 0; g < 2; g++) {
            const u16* qrow = Qa + ((size_t)bh * SEQ + qm + g * 64 + i_l) * 128;
#pragma unroll
            for (int s = 0; s < 4; s++) qf[g][s] = ldfrag(qrow + s * 32 + lq * 8);
        }

        f32x4 Ot[2][4];
#pragma unroll
        for (int g = 0; g < 2; g++)
#pragma unroll
            for (int i = 0; i < 4; i++) { f32x4 z = {0.f, 0.f, 0.f, 0.f}; Ot[g][i] = z; }
        float lsum[2] = {0.f, 0.f};

        {
            int4 a0 = *(const int4*)kq[0];
            int4 a1 = *(const int4*)kq[1];
            int4 a2 = *(const int4*)kq[2];
            int4 a3 = *(const int4*)kq[3];
            int4 b0 = *(const int4*)vq[0];
            int4 b1 = *(const int4*)vq[1];
            *(int4*)&sK[0][(size_t)(0 * 512 + t) * 8] = a0;
            *(int4*)&sK[0][(size_t)(1 * 512 + t) * 8] = a1;
            *(int4*)&sK[0][(size_t)(2 * 512 + t) * 8] = a2;
            *(int4*)&sK[0][(size_t)(3 * 512 + t) * 8] = a3;
            *(int4*)&sVt[0][(size_t)(0 * 512 + t) * 8] = b0;
            *(int4*)&sVt[0][(size_t)(1 * 512 + t) * 8] = b1;
        }
        __syncthreads();

        int cur = 0;
        for (int kt = 0; kt <= qt; kt++) {
            const bool pf = kt < qt;
            int4 rk0, rk1, rk2, rk3, rv0, rv1;
            if (pf) {
                const int kn = (kt + 1) * 128;
                rk0 = *(const int4*)(kq[0] + (size_t)kn * 128);
                rk1 = *(const int4*)(kq[1] + (size_t)kn * 128);
                rk2 = *(const int4*)(kq[2] + (size_t)kn * 128);
                rk3 = *(const int4*)(kq[3] + (size_t)kn * 128);
                rv0 = *(const int4*)(vq[0] + kn);
                rv1 = *(const int4*)(vq[1] + kn);
            }
            const u16* sKc = sK[cur];
            const u16* sVc = sVt[cur];

            f32x4 sc[2][4];
#pragma unroll
            for (int g = 0; g < 2; g++)
#pragma unroll
                for (int m = 0; m < 4; m++) { f32x4 z = {0.f,0.f,0.f,0.f}; sc[g][m] = z; }
            __builtin_amdgcn_s_setprio(1);
#pragma unroll
            for (int mt2 = 0; mt2 < 4; mt2++) {
                int j = wk * 64 + mt2 * 16 + lr;
#pragma unroll
                for (int s = 0; s < 4; s++) {
                    bf16x8 kf = ldfrag(&sKc[(j * 16 + ((s * 4 + lq) ^ (j & 15))) * 8]);
                    sc[0][mt2] = MFMA16(kf, qf[0][s], sc[0][mt2]);
                    sc[1][mt2] = MFMA16(kf, qf[1][s], sc[1][mt2]);
                }
            }
            __builtin_amdgcn_s_setprio(0);
            if (kt == qt) {
#pragma unroll
                for (int mt2 = 0; mt2 < 4; mt2++)
#pragma unroll
                    for (int r = 0; r < 4; r++) {
                        int jj = wk * 64 + mt2 * 16 + lq * 4 + r;
                        if (jj > i_l)      sc[0][mt2][r] = -INFINITY;
                        if (jj > 64 + i_l) sc[1][mt2][r] = -INFINITY;
                    }
            }
#pragma unroll
            for (int g = 0; g < 2; g++) {
#pragma unroll
                for (int mt2 = 0; mt2 < 4; mt2++) {
                    float e0 = __builtin_amdgcn_exp2f(sc[g][mt2][0]);
                    float e1 = __builtin_amdgcn_exp2f(sc[g][mt2][1]);
                    float e2 = __builtin_amdgcn_exp2f(sc[g][mt2][2]);
                    float e3 = __builtin_amdgcn_exp2f(sc[g][mt2][3]);
                    lsum[g] += (e0 + e1) + (e2 + e3);
                    *(u16x4*)&sP[(g * 64 + i_l) * 136 + wk * 64 + mt2 * 16 + lq * 4] =
                        pack4(e0, e1, e2, e3);
                }
            }
            __builtin_amdgcn_s_setprio(1);
#pragma unroll
            for (int s2l = 0; s2l < 2; s2l++) {
                bf16x8 pf0 = ldfrag(&sP[(i_l) * 136 + wk * 64 + s2l * 32 + lq * 8]);
                bf16x8 pf1 = ldfrag(&sP[(64 + i_l) * 136 + wk * 64 + s2l * 32 + lq * 8]);
#pragma unroll
                for (int mt = 0; mt < 4; mt++) {
                    int d = mt * 16 + lr;
                    bf16x8 vf = ldfrag(
                        &sVc[(d * 16 + ((wk * 8 + s2l * 4 + lq) ^ (d & 7))) * 8]);
                    Ot[0][mt] = MFMA16(vf, pf0, Ot[0][mt]);
                    Ot[1][mt] = MFMA16(vf, pf1, Ot[1][mt]);
                }
            }
            __builtin_amdgcn_s_setprio(0);
            if (pf) {
                *(int4*)&sK[cur ^ 1][(size_t)(0 * 512 + t) * 8] = rk0;
                *(int4*)&sK[cur ^ 1][(size_t)(1 * 512 + t) * 8] = rk1;
                *(int4*)&sK[cur ^ 1][(size_t)(2 * 512 + t) * 8] = rk2;
                *(int4*)&sK[cur ^ 1][(size_t)(3 * 512 + t) * 8] = rk3;
                *(int4*)&sVt[cur ^ 1][(size_t)(0 * 512 + t) * 8] = rv0;
                *(int4*)&sVt[cur ^ 1][(size_t)(1 * 512 + t) * 8] = rv1;
            }
            __syncthreads();
            cur ^= 1;
        }

        // ---- combine k-split partials and write this segment's output ----
#pragma unroll
        for (int g = 0; g < 2; g++) {
            lsum[g] += __shfl_xor(lsum[g], 16);
            lsum[g] += __shfl_xor(lsum[g], 32);
            sLs[wk][wq][L][g] = lsum[g];
        }
        if (wk == 1) {
            float* dst = &sOt[wq * 64 + L];
#pragma unroll
            for (int g = 0; g < 2; g++)
#pragma unroll
                for (int mt = 0; mt < 4; mt++)
#pragma unroll
                    for (int r = 0; r < 4; r++)
                        dst[256 * (g * 16 + mt * 4 + r)] = Ot[g][mt][r];
        }
        __syncthreads();
        if (wk == 0) {
            const float* src = &sOt[wq * 64 + L];
#pragma unroll
            for (int g = 0; g < 2; g++) {
                float ls = lsum[g] + sLs[1][wq][L][g];
                const float r0 = __builtin_amdgcn_rcpf(ls);
                const float inv = r0 * (2.0f - ls * r0);  // NR refine
                const size_t base =
                    ((size_t)(b * SEQ + qm + g * 64 + i_l)) * EMB + h * HD;
#pragma unroll
                for (int mt = 0; mt < 4; mt++)
                    *(u16x4*)&attn[base + mt * 16 + lq * 4] = pack4(
                        (Ot[g][mt][0] + src[256 * (g * 16 + mt * 4 + 0)]) * inv,
                        (Ot[g][mt][1] + src[256 * (g * 16 + mt * 4 + 1)]) * inv,
                        (Ot[g][mt][2] + src[256 * (g * 16 + mt * 4 + 2)]) * inv,
                        (Ot[g][mt][3] + src[256 * (g * 16 + mt * 4 + 3)]) * inv);
            }
        }
        __syncthreads();   // protect sOt/sLs before next segment's staging
    }
}

// ---------------------------------------------------------------------------
extern "C" void kernel_launch(void* const* d_in, const int* in_sizes, int n_in,
                              void* d_out, int out_size, void* d_ws, size_t ws_size,
                              hipStream_t stream)
{
    const float* x   = (const float*)d_in[0];
    const float* Wq  = (const float*)d_in[1];
    const float* bq  = (const float*)d_in[2];
    const float* Wk  = (const float*)d_in[3];
    const float* bk  = (const float*)d_in[4];
    const float* Wv  = (const float*)d_in[5];
    const float* bv  = (const float*)d_in[6];
    const float* Wo  = (const float*)d_in[7];
    const float* bo  = (const float*)d_in[8];
    const float* J   = (const float*)d_in[9];
    const float* lam = (const float*)d_in[10];

    u16* ws  = (u16*)d_ws;
    u16* xb  = ws;                                   // 4096*1024 bf16 (reused as attn)
    u16* Wqb = xb  + (size_t)4096 * 1024;
    u16* Wkb = Wqb + (size_t)1024 * 1024;
    u16* Wvb = Wkb + (size_t)1024 * 1024;
    u16* Wob = Wvb + (size_t)1024 * 1024;
    u16* Qa  = Wob + (size_t)1024 * 1024;            // 32*2048*128
    u16* Ka  = Qa  + (size_t)32 * 2048 * 128;        // 32*2048*128
    u16* Vt  = Ka  + (size_t)32 * 2048 * 128;        // 32*64*2048 (b,h,d,s)
    u16* Jb  = Vt  + (size_t)32 * 64 * 2048;         // 16*64*64 bf16 (= ws+29360128)
    u16* attn = xb;                                  // alias: xb dead after QKV
    float* dout = (float*)d_out;

    dim3 blk(256);
    // fp32 -> bf16 for x, the four weight matrices, and J
    cvt_all<<<dim3(4128), blk, 0, stream>>>(x, Wq, Wk, Wv, Wo, J, ws);
    // fused Q/K/V projections + Ka[:,64:128]: 64-row tiles, pipelined staging
    qkv_gemm<<<dim3(8, 64, 3), blk, 0, stream>>>(
        xb, Wqb, bq, Wkb, bk, Wvb, bv, lam, Jb, Qa, Ka, Vt);
    // causal flash attention: 256 blocks x 512 thr, qt pair (p, 15-p) per block
    flash<<<dim3(256), dim3(512), 0, stream>>>(Qa, Ka, Vt, attn);
    // output projection (64-row tiles -> 512 blocks, frozen R7 structure)
    gemm_epi<2><<<dim3(8, 64), blk, 0, stream>>>(attn, Wob, bo, dout);
}

// Round 11
// 183.425 us; speedup vs baseline: 1.2070x; 1.0673x over previous
//
#include <hip/hip_runtime.h>
#include <hip/hip_bf16.h>

typedef unsigned short u16;
typedef __bf16 bf16x8 __attribute__((ext_vector_type(8)));
typedef float f32x4 __attribute__((ext_vector_type(4)));
typedef unsigned short u16x4 __attribute__((ext_vector_type(4)));

#define MFMA16(a, b, c) __builtin_amdgcn_mfma_f32_16x16x32_bf16(a, b, c, 0, 0, 0)

#define EMB 1024
#define SEQ 2048
#define NH 16
#define HD 64
#define LOG2E 1.4426950408889634f

// async global->LDS, 16B per lane; LDS dest = wave-uniform base + lane*16
#define GLOAD_LDS16(g, l) __builtin_amdgcn_global_load_lds( \
    (const __attribute__((address_space(1))) unsigned int*)(g), \
    (__attribute__((address_space(3))) unsigned int*)(l), 16, 0, 0)

__device__ __forceinline__ float b2f(u16 u) {
    union { unsigned int i; float f; } v; v.i = ((unsigned int)u) << 16; return v.f;
}
__device__ __forceinline__ u16 f2b(float f) {
    __hip_bfloat16 h = __float2bfloat16(f);
    return *reinterpret_cast<u16*>(&h);
}
__device__ __forceinline__ u16x4 pack4(float a, float b, float c, float d) {
    union { __hip_bfloat162 h2[2]; u16x4 u; } r;
    r.h2[0] = __float22bfloat162_rn(float2{a, b});
    r.h2[1] = __float22bfloat162_rn(float2{c, d});
    return r.u;
}
__device__ __forceinline__ bf16x8 ldfrag(const u16* p) {
    return *reinterpret_cast<const bf16x8*>(p);
}
__device__ __forceinline__ bf16x8 cvt8(const float* p) {
    const float4 a = *reinterpret_cast<const float4*>(p);
    const float4 b = *reinterpret_cast<const float4*>(p + 4);
    union { u16x4 q[2]; bf16x8 v; } r;
    r.q[0] = pack4(a.x, a.y, a.z, a.w);
    r.q[1] = pack4(b.x, b.y, b.z, b.w);
    return r.v;
}
// tanh via hw exp2 + rcp: rel err < 1e-6, safe for |x| < 40
__device__ __forceinline__ float fast_tanh(float x) {
    float t = __builtin_amdgcn_exp2f(x * (2.0f * LOG2E));
    return 1.0f - 2.0f * __builtin_amdgcn_rcpf(t + 1.0f);
}

// ---------------------------------------------------------------------------
// fp32 -> bf16: [x (4096x1024) | Wq | Wk | Wv | Wo] -> ws bf16, and
// J (16x64x64) -> Jb at ws + 29360128 (u16 elems)
// ---------------------------------------------------------------------------
__global__ __launch_bounds__(256) void cvt_all(
        const float* __restrict__ x,  const float* __restrict__ Wq,
        const float* __restrict__ Wk, const float* __restrict__ Wv,
        const float* __restrict__ Wo, const float* __restrict__ J,
        u16* __restrict__ dst)
{
    size_t i = ((size_t)blockIdx.x * 256 + threadIdx.x) * 8;
    const float* src; size_t off; u16* d;
    if (i < 4194304) { src = x; off = i; d = dst + i; }
    else if (i < 8388608) {
        size_t j = i - 4194304; int w = (int)(j >> 20); off = j & 1048575;
        src = (w == 0) ? Wq : (w == 1) ? Wk : (w == 2) ? Wv : Wo;
        d = dst + i;
    } else {
        off = i - 8388608; src = J; d = dst + 29360128 + off;
    }
    *(bf16x8*)d = cvt8(src + off);
}

// ---------------------------------------------------------------------------
// GEMM: C = A(MxK,bf16) @ W(NxK,bf16)^T + bias(fp32). Tile MI*32 x 128, BK=64.
// ROUND 11: revert to the FROZEN round-7 structure (global_load_lds staging,
// 2 barriers per K-step, C^T accumulators, vectorized epilogues; 48.2 µs).
// Rounds 6/8/9/10 all regressed trying to re-schedule the staging -> frozen.
// Single change this round: XCD-aware block orientation (T1) — m-tiles now on
// blockIdx.x (fast-varying): XCD k's L2 holds only A panels m = k (mod 8)
// (1 MB, resident across all 24 (n,z) visitors) instead of every XCD pulling
// the full 8 MB A. W becomes the per-XCD-replicated operand (3 MB, read once
// each). Aggregate L3->L2 traffic ~70 -> ~32 MB; per-K-step DMA drain hits
// L2 more often (the exposed-latency stall shrinks). Pure index remap.
// ---------------------------------------------------------------------------
template<int MI>   // m-frags per wave (4 -> 128-row tile, 2 -> 64-row tile)
__global__ __launch_bounds__(256, 4) void gemm_epi(
        const u16* __restrict__ A,
        const u16* __restrict__ W0, const float* __restrict__ B0,
        const u16* __restrict__ W1, const float* __restrict__ B1,
        const u16* __restrict__ W2, const float* __restrict__ B2,
        const float* __restrict__ lam, const u16* __restrict__ Jb,
        u16* __restrict__ Qa, u16* __restrict__ Ka, u16* __restrict__ Vt,
        float* __restrict__ out, int modeBase)
{
    const int mode = modeBase + blockIdx.z;
    const u16* W; const float* bias;
    if (blockIdx.z == 0)      { W = W0; bias = B0; }
    else if (blockIdx.z == 1) { W = W1; bias = B1; }
    else                      { W = W2; bias = B2; }

    __shared__ __attribute__((aligned(16))) u16 sA[MI * 32 * 64];
    __shared__ __attribute__((aligned(16))) u16 sB[128 * 64];

    const int t = threadIdx.x;
    const int w = t >> 6, L = t & 63;
    const int wm = w >> 1, wn = w & 1;
    const int lr = L & 15, lq = L >> 4;
    const int wbase = t & 192;                   // wave*64
    // T1 orientation: m on blockIdx.x (fast) -> XCD-local A panels
    const int m0 = blockIdx.x * (MI * 32), n0 = blockIdx.y * 128;

    f32x4 acc[MI][4];
#pragma unroll
    for (int i = 0; i < MI; i++)
#pragma unroll
        for (int j = 0; j < 4; j++) { f32x4 z = {0.f, 0.f, 0.f, 0.f}; acc[i][j] = z; }

    for (int k0 = 0; k0 < EMB; k0 += 64) {
        __syncthreads();
        // stage A: MI*256 chunks of 8 elems (8 chunks/row), col8 = cc ^ (row&7)
#pragma unroll
        for (int q = 0; q < MI; q++) {
            int c = q * 256 + t;
            int row = c >> 3, cc = c & 7;
            int col8 = cc ^ (row & 7);
            GLOAD_LDS16(&A[(size_t)(m0 + row) * EMB + k0 + col8 * 8],
                        &sA[(q * 256 + wbase) * 8]);
        }
        // stage B: 1024 chunks
#pragma unroll
        for (int q = 0; q < 4; q++) {
            int c = q * 256 + t;
            int row = c >> 3, cc = c & 7;
            int col8 = cc ^ (row & 7);
            GLOAD_LDS16(&W[(size_t)(n0 + row) * EMB + k0 + col8 * 8],
                        &sB[(q * 256 + wbase) * 8]);
        }
        __syncthreads();
        // two 32-k sub-chunks; fragments loaded per sub-chunk to bound VGPR
#pragma unroll
        for (int s = 0; s < 2; s++) {
            bf16x8 af[MI], bfr[4];
#pragma unroll
            for (int mi = 0; mi < MI; mi++) {
                int row = wm * (MI * 16) + mi * 16 + lr;
                af[mi] = ldfrag(&sA[(row * 8 + ((s * 4 + lq) ^ (row & 7))) * 8]);
            }
#pragma unroll
            for (int ni = 0; ni < 4; ni++) {
                int row = wn * 64 + ni * 16 + lr;
                bfr[ni] = ldfrag(&sB[(row * 8 + ((s * 4 + lq) ^ (row & 7))) * 8]);
            }
            // C^T: A-op = W-frag (rows = n), B-op = x-frag (rows = s)
#pragma unroll
            for (int mi = 0; mi < MI; mi++)
#pragma unroll
                for (int ni = 0; ni < 4; ni++)
                    acc[mi][ni] = MFMA16(bfr[ni], af[mi], acc[mi][ni]);
        }
    }

    // mode 1 reuses sA/sB for tanh(K); main-loop frag reads must be done
    if (mode == 1) __syncthreads();
    u16* sU = (w < 2) ? &sA[(size_t)w * 4096] : &sB[(size_t)(w - 2) * 4096];

    const float lamf = lam[0];
    const float qsc = 0.125f * LOG2E, lsc = lamf * LOG2E;
#pragma unroll
    for (int mi = 0; mi < MI; mi++)
#pragma unroll
        for (int ni = 0; ni < 4; ni++) {
            // C^T mapping: col (lr) = s axis, row (lq*4+r) = n/d axis
            const int sg = m0 + wm * (MI * 16) + mi * 16 + lr;
            const int ng = n0 + wn * 64 + ni * 16 + lq * 4;   // 4 consecutive n
            const float4 bv4 = *(const float4*)&bias[ng];
            const float v0 = acc[mi][ni][0] + bv4.x;
            const float v1 = acc[mi][ni][1] + bv4.y;
            const float v2 = acc[mi][ni][2] + bv4.z;
            const float v3 = acc[mi][ni][3] + bv4.w;
            if (mode == 3) {
                float4 o = {v0, v1, v2, v3};
                *(float4*)&out[(size_t)sg * EMB + ng] = o;
            } else {
                const int b = sg >> 11, s0 = sg & 2047;
                const int h = ng >> 6, d0 = ng & 63;
                if (mode == 0) {
                    size_t i128 = ((size_t)(b * NH + h) * SEQ + s0) * 128 + d0;
                    *(u16x4*)&Qa[i128] = pack4(v0 * qsc, v1 * qsc, v2 * qsc, v3 * qsc);
                    *(u16x4*)&Qa[i128 + 64] =
                        pack4(lsc * fast_tanh(v0), lsc * fast_tanh(v1),
                              lsc * fast_tanh(v2), lsc * fast_tanh(v3));
                } else if (mode == 1) {
                    *(u16x4*)&Ka[((size_t)(b * NH + h) * SEQ + s0) * 128 + d0] =
                        pack4(v0, v1, v2, v3);
                    // stage tanh(K) into per-wave LDS [64][64], XOR chunk swizzle
                    const int sl = mi * 16 + lr;             // local s row
                    const int chunk = (d0 >> 3) ^ (sl & 7);
                    *(u16x4*)&sU[sl * 64 + chunk * 8 + (d0 & 7)] =
                        pack4(fast_tanh(v0), fast_tanh(v1),
                              fast_tanh(v2), fast_tanh(v3));
                } else {
#pragma unroll
                    for (int r = 0; r < 4; r++) {
                        float vr = (r == 0) ? v0 : (r == 1) ? v1 : (r == 2) ? v2 : v3;
                        Vt[((size_t)(b * NH + h) * HD + d0 + r) * SEQ + s0] = f2b(vr);
                    }
                }
            }
        }

    // fused U kernel: Ka[:,64:128] = tanh(K) @ J_h^T (C^T orientation:
    // A-op = J rows (d_out), B-op = tanh rows (s))
    if (mode == 1) {
        const int hn = (n0 >> 6) + wn;
        const u16* Jh = Jb + (size_t)hn * 4096;
        bf16x8 jf[4][2];
#pragma unroll
        for (int nt = 0; nt < 4; nt++)
#pragma unroll
            for (int s2 = 0; s2 < 2; s2++)
                jf[nt][s2] = ldfrag(&Jh[(nt * 16 + lr) * 64 + s2 * 32 + lq * 8]);
#pragma unroll
        for (int rt2 = 0; rt2 < 4; rt2++) {
            int r64 = rt2 * 16 + lr;
            bf16x8 a0 = ldfrag(&sU[r64 * 64 + ((0 + lq) ^ (r64 & 7)) * 8]);
            bf16x8 a1 = ldfrag(&sU[r64 * 64 + ((4 + lq) ^ (r64 & 7)) * 8]);
            const int grow = m0 + wm * 64 + rt2 * 16 + lr;   // s (col axis)
            const int bb = grow >> 11, ss = grow & 2047;
            const size_t kbase = ((size_t)(bb * NH + hn) * SEQ + ss) * 128 + 64;
#pragma unroll
            for (int nt = 0; nt < 4; nt++) {
                f32x4 acc2 = {0.f, 0.f, 0.f, 0.f};
                acc2 = MFMA16(jf[nt][0], a0, acc2);
                acc2 = MFMA16(jf[nt][1], a1, acc2);
                *(u16x4*)&Ka[kbase + nt * 16 + lq * 4] =
                    pack4(acc2[0], acc2[1], acc2[2], acc2[3]);
            }
        }
    }
}

// ---------------------------------------------------------------------------
// Causal flash, S^T formulation, BM=128, 256 blocks x 512 thr (8 waves),
// segments (qt=p, qt=15-p) per block = uniform 17 k-tiles of KVBLK=128.
// (unchanged from round 4)
// ---------------------------------------------------------------------------
__global__ __launch_bounds__(512) void flash(
        const u16* __restrict__ Qa, const u16* __restrict__ Ka,
        const u16* __restrict__ Vt, u16* __restrict__ attn)
{
    __shared__ __attribute__((aligned(16))) u16 sK[2][128 * 128];  // 64 KB
    __shared__ __attribute__((aligned(16))) u16 sVt[2][64 * 128];  // 32 KB
    __shared__ __attribute__((aligned(16))) u16 sP[128 * 136];     // 34 KB
    __shared__ float sLs[2][4][64][2];                             // 4 KB

    const int t = threadIdx.x, w = t >> 6, L = t & 63, lr = L & 15, lq = L >> 4;
    const int wq = w & 3, wk = w >> 2;
    const int bh = blockIdx.x & 31, p = blockIdx.x >> 5;
    const int i_l = wq * 16 + lr;           // lane's q-row within a 64-set
    const u16* Kbase = Ka + (size_t)bh * SEQ * 128;
    const u16* Vbase = Vt + (size_t)bh * HD * SEQ;
    const int b = bh >> 4, h = bh & 15;
    float* sOt = reinterpret_cast<float*>(sK);   // 32 KB combine buffer (fits)

    const u16* kq[4];
#pragma unroll
    for (int q = 0; q < 4; q++) {
        int c = q * 512 + t;
        int row = c >> 4, cc = c & 15;
        kq[q] = Kbase + (size_t)row * 128 + (cc ^ (row & 15)) * 8;
    }
    const u16* vq[2];
#pragma unroll
    for (int q = 0; q < 2; q++) {
        int c = q * 512 + t;
        int d = c >> 4, cc = c & 15;
        vq[q] = Vbase + (size_t)d * SEQ + (cc ^ (d & 7)) * 8;
    }

#pragma unroll 1
    for (int seg = 0; seg < 2; seg++) {
        const int qt = seg ? 15 - p : p;
        const int qm = qt * 128;

        bf16x8 qf[2][4];
#pragma unroll
        for (int g = 0; g < 2; g++) {
            const u16* qrow = Qa + ((size_t)bh * SEQ + qm + g * 64 + i_l) * 128;
#pragma unroll
            for (int s = 0; s < 4; s++) qf[g][s] = ldfrag(qrow + s * 32 + lq * 8);
        }

        f32x4 Ot[2][4];
#pragma unroll
        for (int g = 0; g < 2; g++)
#pragma unroll
            for (int i = 0; i < 4; i++) { f32x4 z = {0.f, 0.f, 0.f, 0.f}; Ot[g][i] = z; }
        float lsum[2] = {0.f, 0.f};

        {
            int4 a0 = *(const int4*)kq[0];
            int4 a1 = *(const int4*)kq[1];
            int4 a2 = *(const int4*)kq[2];
            int4 a3 = *(const int4*)kq[3];
            int4 b0 = *(const int4*)vq[0];
            int4 b1 = *(const int4*)vq[1];
            *(int4*)&sK[0][(size_t)(0 * 512 + t) * 8] = a0;
            *(int4*)&sK[0][(size_t)(1 * 512 + t) * 8] = a1;
            *(int4*)&sK[0][(size_t)(2 * 512 + t) * 8] = a2;
            *(int4*)&sK[0][(size_t)(3 * 512 + t) * 8] = a3;
            *(int4*)&sVt[0][(size_t)(0 * 512 + t) * 8] = b0;
            *(int4*)&sVt[0][(size_t)(1 * 512 + t) * 8] = b1;
        }
        __syncthreads();

        int cur = 0;
        for (int kt = 0; kt <= qt; kt++) {
            const bool pf = kt < qt;
            int4 rk0, rk1, rk2, rk3, rv0, rv1;
            if (pf) {
                const int kn = (kt + 1) * 128;
                rk0 = *(const int4*)(kq[0] + (size_t)kn * 128);
                rk1 = *(const int4*)(kq[1] + (size_t)kn * 128);
                rk2 = *(const int4*)(kq[2] + (size_t)kn * 128);
                rk3 = *(const int4*)(kq[3] + (size_t)kn * 128);
                rv0 = *(const int4*)(vq[0] + kn);
                rv1 = *(const int4*)(vq[1] + kn);
            }
            const u16* sKc = sK[cur];
            const u16* sVc = sVt[cur];

            f32x4 sc[2][4];
#pragma unroll
            for (int g = 0; g < 2; g++)
#pragma unroll
                for (int m = 0; m < 4; m++) { f32x4 z = {0.f,0.f,0.f,0.f}; sc[g][m] = z; }
            __builtin_amdgcn_s_setprio(1);
#pragma unroll
            for (int mt2 = 0; mt2 < 4; mt2++) {
                int j = wk * 64 + mt2 * 16 + lr;
#pragma unroll
                for (int s = 0; s < 4; s++) {
                    bf16x8 kf = ldfrag(&sKc[(j * 16 + ((s * 4 + lq) ^ (j & 15))) * 8]);
                    sc[0][mt2] = MFMA16(kf, qf[0][s], sc[0][mt2]);
                    sc[1][mt2] = MFMA16(kf, qf[1][s], sc[1][mt2]);
                }
            }
            __builtin_amdgcn_s_setprio(0);
            if (kt == qt) {
#pragma unroll
                for (int mt2 = 0; mt2 < 4; mt2++)
#pragma unroll
                    for (int r = 0; r < 4; r++) {
                        int jj = wk * 64 + mt2 * 16 + lq * 4 + r;
                        if (jj > i_l)      sc[0][mt2][r] = -INFINITY;
                        if (jj > 64 + i_l) sc[1][mt2][r] = -INFINITY;
                    }
            }
#pragma unroll
            for (int g = 0; g < 2; g++) {
#pragma unroll
                for (int mt2 = 0; mt2 < 4; mt2++) {
                    float e0 = __builtin_amdgcn_exp2f(sc[g][mt2][0]);
                    float e1 = __builtin_amdgcn_exp2f(sc[g][mt2][1]);
                    float e2 = __builtin_amdgcn_exp2f(sc[g][mt2][2]);
                    float e3 = __builtin_amdgcn_exp2f(sc[g][mt2][3]);
                    lsum[g] += (e0 + e1) + (e2 + e3);
                    *(u16x4*)&sP[(g * 64 + i_l) * 136 + wk * 64 + mt2 * 16 + lq * 4] =
                        pack4(e0, e1, e2, e3);
                }
            }
            __builtin_amdgcn_s_setprio(1);
#pragma unroll
            for (int s2l = 0; s2l < 2; s2l++) {
                bf16x8 pf0 = ldfrag(&sP[(i_l) * 136 + wk * 64 + s2l * 32 + lq * 8]);
                bf16x8 pf1 = ldfrag(&sP[(64 + i_l) * 136 + wk * 64 + s2l * 32 + lq * 8]);
#pragma unroll
                for (int mt = 0; mt < 4; mt++) {
                    int d = mt * 16 + lr;
                    bf16x8 vf = ldfrag(
                        &sVc[(d * 16 + ((wk * 8 + s2l * 4 + lq) ^ (d & 7))) * 8]);
                    Ot[0][mt] = MFMA16(vf, pf0, Ot[0][mt]);
                    Ot[1][mt] = MFMA16(vf, pf1, Ot[1][mt]);
                }
            }
            __builtin_amdgcn_s_setprio(0);
            if (pf) {
                *(int4*)&sK[cur ^ 1][(size_t)(0 * 512 + t) * 8] = rk0;
                *(int4*)&sK[cur ^ 1][(size_t)(1 * 512 + t) * 8] = rk1;
                *(int4*)&sK[cur ^ 1][(size_t)(2 * 512 + t) * 8] = rk2;
                *(int4*)&sK[cur ^ 1][(size_t)(3 * 512 + t) * 8] = rk3;
                *(int4*)&sVt[cur ^ 1][(size_t)(0 * 512 + t) * 8] = rv0;
                *(int4*)&sVt[cur ^ 1][(size_t)(1 * 512 + t) * 8] = rv1;
            }
            __syncthreads();
            cur ^= 1;
        }

        // ---- combine k-split partials and write this segment's output ----
#pragma unroll
        for (int g = 0; g < 2; g++) {
            lsum[g] += __shfl_xor(lsum[g], 16);
            lsum[g] += __shfl_xor(lsum[g], 32);
            sLs[wk][wq][L][g] = lsum[g];
        }
        if (wk == 1) {
            float* dst = &sOt[wq * 64 + L];
#pragma unroll
            for (int g = 0; g < 2; g++)
#pragma unroll
                for (int mt = 0; mt < 4; mt++)
#pragma unroll
                    for (int r = 0; r < 4; r++)
                        dst[256 * (g * 16 + mt * 4 + r)] = Ot[g][mt][r];
        }
        __syncthreads();
        if (wk == 0) {
            const float* src = &sOt[wq * 64 + L];
#pragma unroll
            for (int g = 0; g < 2; g++) {
                float ls = lsum[g] + sLs[1][wq][L][g];
                const float r0 = __builtin_amdgcn_rcpf(ls);
                const float inv = r0 * (2.0f - ls * r0);  // NR refine
                const size_t base =
                    ((size_t)(b * SEQ + qm + g * 64 + i_l)) * EMB + h * HD;
#pragma unroll
                for (int mt = 0; mt < 4; mt++)
                    *(u16x4*)&attn[base + mt * 16 + lq * 4] = pack4(
                        (Ot[g][mt][0] + src[256 * (g * 16 + mt * 4 + 0)]) * inv,
                        (Ot[g][mt][1] + src[256 * (g * 16 + mt * 4 + 1)]) * inv,
                        (Ot[g][mt][2] + src[256 * (g * 16 + mt * 4 + 2)]) * inv,
                        (Ot[g][mt][3] + src[256 * (g * 16 + mt * 4 + 3)]) * inv);
            }
        }
        __syncthreads();   // protect sOt/sLs before next segment's staging
    }
}

// ---------------------------------------------------------------------------
extern "C" void kernel_launch(void* const* d_in, const int* in_sizes, int n_in,
                              void* d_out, int out_size, void* d_ws, size_t ws_size,
                              hipStream_t stream)
{
    const float* x   = (const float*)d_in[0];
    const float* Wq  = (const float*)d_in[1];
    const float* bq  = (const float*)d_in[2];
    const float* Wk  = (const float*)d_in[3];
    const float* bk  = (const float*)d_in[4];
    const float* Wv  = (const float*)d_in[5];
    const float* bv  = (const float*)d_in[6];
    const float* Wo  = (const float*)d_in[7];
    const float* bo  = (const float*)d_in[8];
    const float* J   = (const float*)d_in[9];
    const float* lam = (const float*)d_in[10];

    u16* ws  = (u16*)d_ws;
    u16* xb  = ws;                                   // 4096*1024 bf16 (reused as attn)
    u16* Wqb = xb  + (size_t)4096 * 1024;
    u16* Wkb = Wqb + (size_t)1024 * 1024;
    u16* Wvb = Wkb + (size_t)1024 * 1024;
    u16* Wob = Wvb + (size_t)1024 * 1024;
    u16* Qa  = Wob + (size_t)1024 * 1024;            // 32*2048*128
    u16* Ka  = Qa  + (size_t)32 * 2048 * 128;        // 32*2048*128
    u16* Vt  = Ka  + (size_t)32 * 2048 * 128;        // 32*64*2048 (b,h,d,s)
    u16* Jb  = Vt  + (size_t)32 * 64 * 2048;         // 16*64*64 bf16 (= ws+29360128)
    u16* attn = xb;                                  // alias: xb dead after QKV
    float* dout = (float*)d_out;

    dim3 blk(256);
    // fp32 -> bf16 for x, the four weight matrices, and J
    cvt_all<<<dim3(4128), blk, 0, stream>>>(x, Wq, Wk, Wv, Wo, J, ws);
    // fused Q/K/V projections (BK=64); mode 1 also produces Ka[:,64:128].
    // grid (m-tiles=32 fast, n-tiles=8, z=3): XCD-local A panels (T1)
    gemm_epi<4><<<dim3(32, 8, 3), blk, 0, stream>>>(
        xb, Wqb, bq, Wkb, bk, Wvb, bv, lam, Jb, Qa, Ka, Vt, dout, 0);
    // causal flash attention: 256 blocks x 512 thr, qt pair (p, 15-p) per block
    flash<<<dim3(256), dim3(512), 0, stream>>>(Qa, Ka, Vt, attn);
    // output projection: grid (m-tiles=64 fast, n-tiles=8), frozen R7 structure
    gemm_epi<2><<<dim3(64, 8, 1), blk, 0, stream>>>(
        attn, Wob, bo, Wob, bo, Wob, bo, lam, Jb, Qa, Ka, Vt, dout, 3);
}